// Round 10
// baseline (354.768 us; speedup 1.0000x reference)
//
#include <hip/hip_runtime.h>

// ---------------- problem constants ----------------
#define VOCAB 18
#define EMB   200
#define HID   200
#define G4    800           // 4*HID
#define SEQ   128
#define BATCH 2048
#define MB    8             // batch rows per block
#define NT    56            // N tiles: 50 gate (j-blocked) + 2 logit + 4 zero
#define KS    7             // K steps of 32 -> 224 padded K
                            // k<200: W_hh | k=200: logit bias | k=201+v: tbl[v]
#define TPB   256           // 4 waves -> 1 wave/SIMD -> 512-reg budget
#define TPW   14            // tiles per wave (56/4) -> 392 pinned AGPRs
#define SV    (SEQ*VOCAB)   // 2304
#define LOGITS_N ((size_t)BATCH*SEQ*VOCAB)

typedef short s16x8 __attribute__((ext_vector_type(8)));
typedef float f32x4 __attribute__((ext_vector_type(4)));

__device__ __forceinline__ unsigned short f2bf(float f) {
  unsigned int u = __float_as_uint(f);
  u += 0x7FFFu + ((u >> 16) & 1u);            // RNE; no NaNs in this problem
  return (unsigned short)(u >> 16);
}
__device__ __forceinline__ float sigm(float x) {
  float e = __builtin_amdgcn_exp2f(x * 1.4426950408889634f);
  return e * __builtin_amdgcn_rcpf(e + 1.0f);
}
__device__ __forceinline__ float tanhq(float x) {
  float e = __builtin_amdgcn_exp2f(x * 2.8853900817779268f); // exp2(2x*log2e)
  return 1.0f - 2.0f * __builtin_amdgcn_rcpf(e + 1.0f);
}

// ---------------- prep 1: token table (gate-major cols, bf16 18x800) ------
// tbl[v][colg] = (v!=0)*dot(E[v], W_ih[colg]) + b_ih[colg] + b_hh[colg]
__global__ void prep_tbl(const float* __restrict__ E, const float* __restrict__ W_ih,
                         const float* __restrict__ b_ih, const float* __restrict__ b_hh,
                         unsigned short* __restrict__ tbl) {
  int tid = blockIdx.x * 256 + threadIdx.x;
  if (tid >= VOCAB * G4) return;
  int v = tid / G4, col = tid % G4;
  float s = b_ih[col] + b_hh[col];
  if (v != 0) {
    const float* Er = E + v * EMB;
    const float* Wr = W_ih + col * EMB;
    for (int e = 0; e < EMB; ++e) s += Er[e] * Wr[e];
  }
  tbl[tid] = f2bf(s);
}

// ---------------- prep 2: pack Wp ----------------
// B-frag order: lane l elem i = B[32s+8*(l>>4)+i][tile n, c=(l&15)].
// Gate tiles n<50: c = jj*4+g -> gate g, hid j = 4n+jj; gate-major col = g*200+j.
//   B[k][n,c] = W_hh[(g*200+j)*HID + k]   (k<200)
//             = tbl[k-201][g*200+j]       (201<=k<219)
//             = 0 otherwise (incl. k=200)
// Logit tiles n=50,51: v = 16(n-50)+c:
//   B[k][n,c] = W_out[v*HID+k] (k<200, v<18) | b_out[v] (k==200) | 0
__global__ void prep_wp(const float* __restrict__ W_hh, const float* __restrict__ W_out,
                        const float* __restrict__ b_out,
                        const unsigned short* __restrict__ tbl,
                        short* __restrict__ Wp) {
  int u = blockIdx.x * 256 + threadIdx.x;
  if (u >= NT * KS * 64) return;
  int n    = u / (KS * 64);
  int rem  = u % (KS * 64);
  int s_   = rem >> 6;
  int lane = rem & 63;
  int c    = lane & 15;
  int kb   = lane >> 4;
  s16x8 o;
  #pragma unroll
  for (int i = 0; i < 8; ++i) {
    int k = 32 * s_ + 8 * kb + i;
    short b = 0;
    if (n < 50) {
      int g = c & 3, j = 4 * n + (c >> 2);
      int colg = g * 200 + j;
      if (k < HID)                          b = (short)f2bf(W_hh[colg * HID + k]);
      else if (k >= 201 && k < 201 + VOCAB) b = (short)tbl[(k - 201) * G4 + colg];
    } else if (n < 52) {
      int v = 16 * (n - 50) + c;
      if (v < VOCAB) {
        if (k < HID)       b = (short)f2bf(W_out[v * HID + k]);
        else if (k == HID) b = (short)f2bf(b_out[v]);
      }
    }
    o[i] = b;
  }
  *(s16x8*)(Wp + (size_t)u * 8) = o;
}

// ---------------- main ----------------
// 256 blocks x 8 rows; 4 waves (1/SIMD), 392 pinned weight AGPRs/wave.
// Gate tiles are j-blocked so each wave owns the FULL i,f,g,o set for its j's:
// MFMA -> in-wave scratch transpose -> elementwise (all 64 lanes) -> h to hA,
// with NO gatesL and ONE barrier per step. One-hot is injected into the aF[6]
// register (not stored in hA) -> no one-hot/aF race, rows k>200 of hA stay 0.
__global__ __launch_bounds__(TPB) __attribute__((amdgpu_waves_per_eu(1, 1)))
void lstm_kernel(const int* __restrict__ x, const short* __restrict__ Wp,
                 float* __restrict__ out) {
  __shared__ unsigned short hA[KS * 64 * 8];   // A-frag layout bf16 (7.2KB)
  __shared__ int   xtok[MB * SEQ];             // 4KB
  __shared__ float logL[MB * SV];              // logits buffer (73.7KB)
  __shared__ float scr[4][2][8 * 36];          // per-wave transpose scratch (9.2KB)

  const int tid  = threadIdx.x;
  const int lane = tid & 63;
  const int w    = tid >> 6;                   // wave 0..3
  const int blk  = blockIdx.x;

  // writer base: row 4*(lane>>4)+q at sw[36q]; col c=(lane&15) -> jj=c>>2, g=c&3
  const int wbase = (lane >> 4) * 144 + ((lane & 15) >> 2) * 4 + (lane & 3);
  // reader: r = lane>>3, j8 = lane&7 -> 4 gates contiguous
  const int rbase = (lane >> 3) * 36 + (lane & 7) * 4;
  const int jw = 56 * w;                       // wave's j base

  // h0 = 0; bf16 1.0 at bias row k=200 (elems (400+r)*8, r=0..7)
  for (int i = tid; i < KS * 64 * 8; i += TPB)
    hA[i] = (i >= 3200 && i < 3264 && (i & 7) == 0) ? (unsigned short)0x3F80
                                                    : (unsigned short)0;
  for (int i = tid; i < MB * SEQ; i += TPB) xtok[i] = x[blk * (MB * SEQ) + i];

  // weight fragments: 14 tiles x 7 steps x 4 regs = 392 AGPRs, pinned once.
  s16x8 wf[TPW][KS];
  #pragma unroll
  for (int n = 0; n < TPW; ++n) {
    #pragma unroll
    for (int s = 0; s < KS; ++s) {
      wf[n][s] = *(const s16x8*)(Wp + ((((w * TPW + n) * KS) + s) * 64 + lane) * 8);
      asm volatile("" : "+a"(wf[n][s]));
    }
    asm volatile("" ::: "memory");
  }

  float creg[7] = {0.f, 0.f, 0.f, 0.f, 0.f, 0.f, 0.f};
  __syncthreads();

#define DO_PAIR(P, CC) {                                                          \
    f32x4 aA = {0.f,0.f,0.f,0.f}, aB = {0.f,0.f,0.f,0.f};                         \
    _Pragma("unroll")                                                             \
    for (int s = 0; s < KS; ++s) {                                                \
      aA = __builtin_amdgcn_mfma_f32_16x16x32_bf16(aF[s], wf[2*(P)][s],   aA, 0,0,0); \
      aB = __builtin_amdgcn_mfma_f32_16x16x32_bf16(aF[s], wf[2*(P)+1][s], aB, 0,0,0); \
    }                                                                             \
    float* sc = &scr[w][(P) & 1][0];                                              \
    if (lane < 32) {                                                              \
      float* sw = sc + wbase;                                                     \
      sw[0]  = aA[0]; sw[36] = aA[1]; sw[72] = aA[2]; sw[108] = aA[3];            \
      sw[16] = aB[0]; sw[52] = aB[1]; sw[88] = aB[2]; sw[124] = aB[3];            \
    }                                                                             \
    f32x4 gt = *(const f32x4*)(sc + rbase);                                       \
    float i_ = sigm(gt[0]);                                                       \
    float f_ = sigm(gt[1]);                                                       \
    float g_ = tanhq(gt[2]);                                                      \
    float o_ = sigm(gt[3]);                                                       \
    float cn = f_ * (CC) + i_ * g_;                                               \
    float h  = o_ * tanhq(cn);                                                    \
    (CC) = cn;                                                                    \
    int j = jw + 8 * (P) + (lane & 7);                                            \
    hA[((j >> 5) * 64 + 16 * ((j >> 3) & 3) + (lane >> 3)) * 8 + (j & 7)] = f2bf(h); \
    if (t == SEQ - 1) {                                                           \
      size_t bg = (size_t)blk * MB + (lane >> 3);                                 \
      out[LOGITS_N + bg * HID + j] = h;                                           \
      out[LOGITS_N + (size_t)BATCH * HID + bg * HID + j] = cn;                    \
    }                                                                             \
  }

  #pragma unroll 1
  for (int t = 0; t < SEQ; ++t) {
    // ---- load A fragments; inject one-hot token row into aF[6] in-register ----
    s16x8 aF[KS];
    #pragma unroll
    for (int s = 0; s < KS; ++s) aF[s] = *(const s16x8*)&hA[(s * 64 + lane) * 8];
    {
      int vv = xtok[(lane & 7) * SEQ + t];               // row (lane&15)'s token
      int js = (lane & 8) ? 100 : (vv + 9 - 8 * (lane >> 4)); // elem for k=201+vv
      s16x8 a6 = aF[6];
      #pragma unroll
      for (int e = 0; e < 8; ++e)
        a6[e] = (e == js) ? (short)0x3F80 : a6[e];
      aF[6] = a6;
    }

    if (w < 3) {        // 7 gate pairs: j = 56w .. 56w+55
      DO_PAIR(0, creg[0]); DO_PAIR(1, creg[1]); DO_PAIR(2, creg[2]);
      DO_PAIR(3, creg[3]); DO_PAIR(4, creg[4]); DO_PAIR(5, creg[5]);
      DO_PAIR(6, creg[6]);
    } else {            // 4 gate pairs (j=168..199) + logit tiles (local 8,9)
      DO_PAIR(0, creg[0]); DO_PAIR(1, creg[1]);
      DO_PAIR(2, creg[2]); DO_PAIR(3, creg[3]);
      f32x4 a1 = {0.f,0.f,0.f,0.f}, a2 = {0.f,0.f,0.f,0.f};
      #pragma unroll
      for (int s = 0; s < KS; ++s) {
        a1 = __builtin_amdgcn_mfma_f32_16x16x32_bf16(aF[s], wf[8][s], a1, 0, 0, 0);
        a2 = __builtin_amdgcn_mfma_f32_16x16x32_bf16(aF[s], wf[9][s], a2, 0, 0, 0);
      }
      if (t > 0 && lane < 32) {
        int qrow = (lane >> 4) * 4, c = lane & 15;
        #pragma unroll
        for (int q = 0; q < 4; ++q) {
          if (c < VOCAB)      logL[(qrow + q) * SV + (t - 1) * VOCAB + c]      = a1[q];
          if (c < VOCAB - 16) logL[(qrow + q) * SV + (t - 1) * VOCAB + 16 + c] = a2[q];
        }
      }
    }
    __syncthreads();
  }

  // ---- epilogue: logits for t=SEQ-1 from final h (no one-hot injection:
  // token rows multiply zeroed logit B-cols) ----
  if (w == 3) {
    s16x8 aE[KS];
    #pragma unroll
    for (int s = 0; s < KS; ++s) aE[s] = *(const s16x8*)&hA[(s * 64 + lane) * 8];
    f32x4 a1 = {0.f,0.f,0.f,0.f}, a2 = {0.f,0.f,0.f,0.f};
    #pragma unroll
    for (int s = 0; s < KS; ++s) {
      a1 = __builtin_amdgcn_mfma_f32_16x16x32_bf16(aE[s], wf[8][s], a1, 0, 0, 0);
      a2 = __builtin_amdgcn_mfma_f32_16x16x32_bf16(aE[s], wf[9][s], a2, 0, 0, 0);
    }
    if (lane < 32) {
      int qrow = (lane >> 4) * 4, c = lane & 15;
      #pragma unroll
      for (int q = 0; q < 4; ++q) {
        int base = (qrow + q) * SV + (SEQ - 1) * VOCAB;
        if (c < VOCAB)      logL[base + c]      = a1[q];
        if (c < VOCAB - 16) logL[base + 16 + c] = a2[q];
      }
    }
  }
  __syncthreads();

  // ---- flush logits: block's region is contiguous [blk*8 rows][128][18] ----
  float* dst = out + (size_t)blk * (MB * SV);
  for (int i = tid * 4; i < MB * SV; i += TPB * 4)
    *(f32x4*)&dst[i] = *(const f32x4*)&logL[i];
#undef DO_PAIR
}

extern "C" void kernel_launch(void* const* d_in, const int* in_sizes, int n_in,
                              void* d_out, int out_size, void* d_ws, size_t ws_size,
                              hipStream_t stream) {
  const int*   x     = (const int*)  d_in[0];
  const float* E     = (const float*)d_in[1];
  const float* W_ih  = (const float*)d_in[2];
  const float* W_hh  = (const float*)d_in[3];
  const float* b_ih  = (const float*)d_in[4];
  const float* b_hh  = (const float*)d_in[5];
  const float* W_out = (const float*)d_in[6];
  const float* b_out = (const float*)d_in[7];
  float* out = (float*)d_out;

  // ws layout: tbl 18*800*2 = 28800B | Wp 56*7*64*8*2 = 401408B   (~430KB)
  unsigned short* tbl = (unsigned short*)d_ws;
  short* Wp = (short*)d_ws + VOCAB * G4;

  prep_tbl<<<(VOCAB * G4 + 255) / 256, 256, 0, stream>>>(E, W_ih, b_ih, b_hh, tbl);
  prep_wp<<<(NT * KS * 64 + 255) / 256, 256, 0, stream>>>(W_hh, W_out, b_out, tbl, Wp);
  lstm_kernel<<<BATCH / MB, TPB, 0, stream>>>(x, Wp, out);
}